// Round 2
// baseline (524.675 us; speedup 1.0000x reference)
//
#include <hip/hip_runtime.h>
#include <hip/hip_bf16.h>

#define NNODES 50000
#define NEDGES 800000
#define IN_DIM 128
#define EDGE_DIM 32
#define OUT_DIM 128
#define KDIM 160          // IN_DIM + EDGE_DIM
#define A_STRIDE 168      // 160 + 8 pad: kills 8-way LDS bank conflict, keeps 16B align
#define NS 136            // 128 + 8 pad for node kernel
#define MSTRIDE 132       // fp32 m-tile stride: breaks q-lane 4-way bank conflict

typedef __attribute__((ext_vector_type(8))) short short8;
typedef __attribute__((ext_vector_type(4))) short short4v;
typedef __attribute__((ext_vector_type(4))) float floatx4;

__device__ __forceinline__ short f2bf(float f) {
    union { float f; unsigned u; } v; v.f = f;
    unsigned r = (v.u + 0x7FFFu + ((v.u >> 16) & 1u)) >> 16;  // round-nearest-even
    return (short)r;
}

__device__ __forceinline__ void store_bf4(short* p, floatx4 v) {
    short4v s;
    s.x = f2bf(v.x); s.y = f2bf(v.y); s.z = f2bf(v.z); s.w = f2bf(v.w);
    *(short4v*)p = s;
}

// ---------------------------------------------------------------------------
// Prep: WcatB[n][k] (k<128: W1 = W_ne[:, :128]; k>=128: W_comb = W2 @ W_edge),
//       WselfB[n][k] = W_self — both bf16, BT[n][k] row-major.
// ---------------------------------------------------------------------------
__global__ void prep_weights(const float* __restrict__ W_edge,   // [128][32]
                             const float* __restrict__ W_ne,     // [128][256]
                             const float* __restrict__ W_self,   // [128][128]
                             short* __restrict__ WcatB,          // [128][160]
                             short* __restrict__ WselfB)         // [128][128]
{
    int idx = blockIdx.x * 256 + threadIdx.x;
    if (idx < OUT_DIM * KDIM) {
        int n = idx / KDIM, k = idx - n * KDIM;
        float val;
        if (k < IN_DIM) {
            val = W_ne[n * 256 + k];
        } else {
            int j = k - IN_DIM;
            float s = 0.f;
            for (int kk = 0; kk < 128; ++kk)
                s += W_ne[n * 256 + 128 + kk] * W_edge[kk * 32 + j];
            val = s;
        }
        WcatB[idx] = f2bf(val);
    } else if (idx < OUT_DIM * KDIM + OUT_DIM * IN_DIM) {
        int s = idx - OUT_DIM * KDIM;
        WselfB[s] = f2bf(W_self[s]);
    }
}

// ---------------------------------------------------------------------------
// Counting sort of edges by dst: histogram -> single-block scan -> scatter.
// ---------------------------------------------------------------------------
__global__ void hist_kernel(const int* __restrict__ dst, int* __restrict__ cnt) {
    int e = blockIdx.x * 256 + threadIdx.x;
    if (e < NEDGES) atomicAdd(&cnt[dst[e]], 1);
}

__global__ __launch_bounds__(1024) void scan_kernel(const int* __restrict__ cnt,
                                                    int* __restrict__ off2) {
    __shared__ int bufA[1024], bufB[1024];
    const int CH = 49;                       // 49*1024 = 50176 >= 50000
    int t = threadIdx.x;
    int beg = t * CH, end = min(beg + CH, NNODES);
    int s = 0;
    for (int i = beg; i < end; ++i) s += cnt[i];
    bufA[t] = s;
    __syncthreads();
    int* in = bufA; int* out = bufB;
    for (int off = 1; off < 1024; off <<= 1) {
        out[t] = in[t] + (t >= off ? in[t - off] : 0);
        __syncthreads();
        int* tmp = in; in = out; out = tmp;
    }
    int base = in[t] - s;                    // exclusive prefix of this chunk
    for (int i = beg; i < end; ++i) { off2[i] = base; base += cnt[i]; }
}

__global__ void scatter_kernel(const int* __restrict__ src, const int* __restrict__ dst,
                               int* __restrict__ off2,       // cursor (destroyed)
                               int* __restrict__ esrc, int* __restrict__ eidx,
                               int* __restrict__ edst) {
    int e = blockIdx.x * 256 + threadIdx.x;
    if (e < NEDGES) {
        int d = dst[e];
        int pos = atomicAdd(&off2[d], 1);
        esrc[pos] = src[e];
        eidx[pos] = e;
        edst[pos] = d;
    }
}

// ---------------------------------------------------------------------------
// Edge kernel: 64 dst-sorted edges x 128 outputs, K=160.
// m = relu(A @ B^T + b_ne) -> LDS roundtrip -> per-column run-max over sorted
// dst -> one atomicMax per run (avg run ~16 => ~10x fewer atomics than R1).
// ---------------------------------------------------------------------------
__global__ __launch_bounds__(256) void edge_kernel(
    const float* __restrict__ nfeat, const float* __restrict__ etype,
    const int* __restrict__ esrc, const int* __restrict__ eidx,
    const int* __restrict__ edst, const float* __restrict__ b_ne,
    const short* __restrict__ WcatB, float* __restrict__ outmax)
{
    __shared__ char SM[64512];
    short* As = (short*)SM;                  // 64 *168*2 = 21504 B
    short* Bs = (short*)(SM + 21504);        // 128*168*2 = 43008 B
    float* mbuf = (float*)SM;                // 64 *132*4 = 33792 B (overlay)
    __shared__ int dsts[64];
    const int tid = threadIdx.x;
    const int e0 = blockIdx.x * 64;

    if (tid < 64) dsts[tid] = edst[e0 + tid];

    // --- stage B (128 x 160 bf16, L2-hot) ---
    {
        int r = tid >> 1, h = tid & 1;
        const short8* g = (const short8*)(WcatB + r * KDIM + h * 80);
        short* l = Bs + r * A_STRIDE + h * 80;
        #pragma unroll
        for (int c = 0; c < 10; ++c)
            *(short8*)(l + 8 * c) = g[c];
    }
    // --- stage etype rows (gathered) -> A cols 128..159 ---
    {
        int e = tid >> 2, c = tid & 3;       // 4 threads/edge, 8 floats each
        int ei = eidx[e0 + e];
        const floatx4* row = (const floatx4*)(etype + (size_t)ei * 32);
        floatx4 v0 = row[2 * c];
        floatx4 v1 = row[2 * c + 1];
        store_bf4(As + e * A_STRIDE + IN_DIM + 8 * c, v0);
        store_bf4(As + e * A_STRIDE + IN_DIM + 8 * c + 4, v1);
    }
    // --- stage gathered nfeat rows -> A cols 0..127 ---
    {
        int g = tid & 15, eo = tid >> 4;
        #pragma unroll
        for (int p = 0; p < 4; ++p) {
            int e = eo + p * 16;
            int s = esrc[e0 + e];            // same addr across 16 lanes
            const floatx4* row = (const floatx4*)(nfeat + (size_t)s * 128);
            floatx4 v0 = row[g];
            floatx4 v1 = row[g + 16];
            store_bf4(As + e * A_STRIDE + 4 * g, v0);
            store_bf4(As + e * A_STRIDE + 64 + 4 * g, v1);
        }
    }
    __syncthreads();

    const int lane = tid & 63;
    const int w = tid >> 6;
    const int et = w & 1;                    // edge half: rows et*32..+31
    const int nh = w >> 1;                   // out half: cols nh*64..+63
    const int li = lane & 15, q = lane >> 4;

    floatx4 acc[2][4];
    #pragma unroll
    for (int i = 0; i < 2; ++i)
        #pragma unroll
        for (int j = 0; j < 4; ++j)
            acc[i][j] = (floatx4){0.f, 0.f, 0.f, 0.f};

    const short* Ab = As + (et * 32 + li) * A_STRIDE + q * 8;
    const short* Bb = Bs + (nh * 64 + li) * A_STRIDE + q * 8;
    #pragma unroll
    for (int kk = 0; kk < 5; ++kk) {
        short8 a0 = *(const short8*)(Ab + kk * 32);
        short8 a1 = *(const short8*)(Ab + 16 * A_STRIDE + kk * 32);
        short8 b0 = *(const short8*)(Bb + kk * 32);
        short8 b1 = *(const short8*)(Bb + 16 * A_STRIDE + kk * 32);
        short8 b2 = *(const short8*)(Bb + 32 * A_STRIDE + kk * 32);
        short8 b3 = *(const short8*)(Bb + 48 * A_STRIDE + kk * 32);
        acc[0][0] = __builtin_amdgcn_mfma_f32_16x16x32_bf16(a0, b0, acc[0][0], 0, 0, 0);
        acc[0][1] = __builtin_amdgcn_mfma_f32_16x16x32_bf16(a0, b1, acc[0][1], 0, 0, 0);
        acc[0][2] = __builtin_amdgcn_mfma_f32_16x16x32_bf16(a0, b2, acc[0][2], 0, 0, 0);
        acc[0][3] = __builtin_amdgcn_mfma_f32_16x16x32_bf16(a0, b3, acc[0][3], 0, 0, 0);
        acc[1][0] = __builtin_amdgcn_mfma_f32_16x16x32_bf16(a1, b0, acc[1][0], 0, 0, 0);
        acc[1][1] = __builtin_amdgcn_mfma_f32_16x16x32_bf16(a1, b1, acc[1][1], 0, 0, 0);
        acc[1][2] = __builtin_amdgcn_mfma_f32_16x16x32_bf16(a1, b2, acc[1][2], 0, 0, 0);
        acc[1][3] = __builtin_amdgcn_mfma_f32_16x16x32_bf16(a1, b3, acc[1][3], 0, 0, 0);
    }

    __syncthreads();                         // all fragment reads done before overlay

    // --- m tile -> LDS (relu + bias), C/D layout row = q*4+reg, col = li ---
    float bias[4];
    #pragma unroll
    for (int tb = 0; tb < 4; ++tb) bias[tb] = b_ne[nh * 64 + tb * 16 + li];
    #pragma unroll
    for (int ta = 0; ta < 2; ++ta) {
        #pragma unroll
        for (int r = 0; r < 4; ++r) {
            int el = et * 32 + ta * 16 + q * 4 + r;
            #pragma unroll
            for (int tb = 0; tb < 4; ++tb) {
                int o = nh * 64 + tb * 16 + li;
                float v = acc[ta][tb][r] + bias[tb];
                mbuf[el * MSTRIDE + o] = v > 0.f ? v : 0.f;
            }
        }
    }
    __syncthreads();

    // --- per-column run-max over dst-sorted rows; one atomicMax per run ---
    {
        int c = tid & 127, h = tid >> 7;     // 2 threads/col, 32 rows each
        int r0 = h * 32;
        int curd = dsts[r0];
        float best = mbuf[r0 * MSTRIDE + c];
        #pragma unroll 4
        for (int r = 1; r < 32; ++r) {
            int d = dsts[r0 + r];
            float v = mbuf[(r0 + r) * MSTRIDE + c];
            if (d != curd) {
                atomicMax((int*)outmax + (size_t)curd * 128 + c, __float_as_int(best));
                curd = d; best = v;
            } else {
                best = fmaxf(best, v);
            }
        }
        atomicMax((int*)outmax + (size_t)curd * 128 + c, __float_as_int(best));
    }
}

// ---------------------------------------------------------------------------
// Node kernel (in-place): out = (1+eps)*out_neigh + nfeat @ W_self^T + b_self
// ---------------------------------------------------------------------------
__global__ __launch_bounds__(256) void node_kernel(
    const float* __restrict__ nfeat, const float* __restrict__ b_self,
    const float* __restrict__ eps, const short* __restrict__ WselfB,
    float* __restrict__ out)
{
    __shared__ short As[64 * NS];
    __shared__ short Bs[128 * NS];
    const int tid = threadIdx.x;
    const int n0 = blockIdx.x * 64;

    {
        int r = tid >> 1, h = tid & 1;
        const short8* g = (const short8*)(WselfB + r * 128 + h * 64);
        short* l = Bs + r * NS + h * 64;
        #pragma unroll
        for (int c = 0; c < 8; ++c)
            *(short8*)(l + 8 * c) = g[c];
    }
    {
        int r = tid >> 2, fi = tid & 3;
        int n = n0 + r;
        if (n < NNODES) {
            const floatx4* row = (const floatx4*)(nfeat + (size_t)n * 128);
            #pragma unroll
            for (int p = 0; p < 8; ++p) {
                int f = fi + 4 * p;
                store_bf4(As + r * NS + 4 * f, row[f]);
            }
        } else {
            #pragma unroll
            for (int p = 0; p < 8; ++p) {
                int f = fi + 4 * p;
                *(short4v*)(As + r * NS + 4 * f) = (short4v){0, 0, 0, 0};
            }
        }
    }
    __syncthreads();

    const int lane = tid & 63;
    const int w = tid >> 6;
    const int et = w & 1;
    const int nh = w >> 1;
    const int li = lane & 15, q = lane >> 4;

    floatx4 acc[2][4];
    #pragma unroll
    for (int i = 0; i < 2; ++i)
        #pragma unroll
        for (int j = 0; j < 4; ++j)
            acc[i][j] = (floatx4){0.f, 0.f, 0.f, 0.f};

    const short* Ab = As + (et * 32 + li) * NS + q * 8;
    const short* Bb = Bs + (nh * 64 + li) * NS + q * 8;
    #pragma unroll
    for (int kk = 0; kk < 4; ++kk) {
        short8 a0 = *(const short8*)(Ab + kk * 32);
        short8 a1 = *(const short8*)(Ab + 16 * NS + kk * 32);
        short8 b0 = *(const short8*)(Bb + kk * 32);
        short8 b1 = *(const short8*)(Bb + 16 * NS + kk * 32);
        short8 b2 = *(const short8*)(Bb + 32 * NS + kk * 32);
        short8 b3 = *(const short8*)(Bb + 48 * NS + kk * 32);
        acc[0][0] = __builtin_amdgcn_mfma_f32_16x16x32_bf16(a0, b0, acc[0][0], 0, 0, 0);
        acc[0][1] = __builtin_amdgcn_mfma_f32_16x16x32_bf16(a0, b1, acc[0][1], 0, 0, 0);
        acc[0][2] = __builtin_amdgcn_mfma_f32_16x16x32_bf16(a0, b2, acc[0][2], 0, 0, 0);
        acc[0][3] = __builtin_amdgcn_mfma_f32_16x16x32_bf16(a0, b3, acc[0][3], 0, 0, 0);
        acc[1][0] = __builtin_amdgcn_mfma_f32_16x16x32_bf16(a1, b0, acc[1][0], 0, 0, 0);
        acc[1][1] = __builtin_amdgcn_mfma_f32_16x16x32_bf16(a1, b1, acc[1][1], 0, 0, 0);
        acc[1][2] = __builtin_amdgcn_mfma_f32_16x16x32_bf16(a1, b2, acc[1][2], 0, 0, 0);
        acc[1][3] = __builtin_amdgcn_mfma_f32_16x16x32_bf16(a1, b3, acc[1][3], 0, 0, 0);
    }

    const float epsv = 1.0f + eps[0];
    #pragma unroll
    for (int ta = 0; ta < 2; ++ta) {
        #pragma unroll
        for (int r = 0; r < 4; ++r) {
            int n = n0 + et * 32 + ta * 16 + q * 4 + r;
            if (n < NNODES) {
                #pragma unroll
                for (int tb = 0; tb < 4; ++tb) {
                    int o = nh * 64 + tb * 16 + li;
                    float v = acc[ta][tb][r] + b_self[o]
                            + epsv * out[(size_t)n * 128 + o];
                    out[(size_t)n * 128 + o] = v;
                }
            }
        }
    }
}

// ---------------------------------------------------------------------------
extern "C" void kernel_launch(void* const* d_in, const int* in_sizes, int n_in,
                              void* d_out, int out_size, void* d_ws, size_t ws_size,
                              hipStream_t stream) {
    const float* nfeat  = (const float*)d_in[0];
    const float* etype  = (const float*)d_in[1];
    const int*   src    = (const int*)d_in[2];
    const int*   dst    = (const int*)d_in[3];
    const float* W_edge = (const float*)d_in[4];
    const float* W_ne   = (const float*)d_in[5];
    const float* b_ne   = (const float*)d_in[6];
    const float* W_self = (const float*)d_in[7];
    const float* b_self = (const float*)d_in[8];
    const float* eps    = (const float*)d_in[9];
    float* out = (float*)d_out;

    char* ws = (char*)d_ws;
    size_t off = 0;
    auto alloc = [&](size_t bytes) { void* p = ws + off; off = (off + bytes + 255) & ~(size_t)255; return p; };
    int*   cnt    = (int*)alloc((size_t)NNODES * 4);
    int*   off2   = (int*)alloc((size_t)NNODES * 4);
    int*   esrc   = (int*)alloc((size_t)NEDGES * 4);
    int*   eidx   = (int*)alloc((size_t)NEDGES * 4);
    int*   edst   = (int*)alloc((size_t)NEDGES * 4);
    short* WcatB  = (short*)alloc((size_t)OUT_DIM * KDIM * 2);
    short* WselfB = (short*)alloc((size_t)OUT_DIM * IN_DIM * 2);

    hipMemsetAsync(cnt, 0, (size_t)NNODES * 4, stream);
    hipMemsetAsync(out, 0, (size_t)NNODES * 128 * sizeof(float), stream);
    prep_weights<<<144, 256, 0, stream>>>(W_edge, W_ne, W_self, WcatB, WselfB);
    hist_kernel<<<(NEDGES + 255) / 256, 256, 0, stream>>>(dst, cnt);
    scan_kernel<<<1, 1024, 0, stream>>>(cnt, off2);
    scatter_kernel<<<(NEDGES + 255) / 256, 256, 0, stream>>>(src, dst, off2,
                                                             esrc, eidx, edst);
    edge_kernel<<<NEDGES / 64, 256, 0, stream>>>(nfeat, etype, esrc, eidx, edst,
                                                 b_ne, WcatB, out);
    node_kernel<<<(NNODES + 63) / 64, 256, 0, stream>>>(nfeat, b_self, eps,
                                                        WselfB, out);
}

// Round 3
// 504.967 us; speedup vs baseline: 1.0390x; 1.0390x over previous
//
#include <hip/hip_runtime.h>
#include <hip/hip_bf16.h>

#define NNODES 50000
#define NEDGES 800000
#define IN_DIM 128
#define EDGE_DIM 32
#define OUT_DIM 128
#define KDIM 160          // IN_DIM + EDGE_DIM
#define A_STRIDE 168      // 160 + 8 pad: kills 8-way LDS bank conflict, keeps 16B align
#define NS 136            // 128 + 8 pad for node kernel
#define MS2 130           // bf16 m-tile stride (even => 2-way bank alias only)
#define NT (NEDGES / 64)  // 12500 tiles
#define EG 512            // edge grid: 2 blocks/CU
#define TPB ((NT + EG - 1) / EG)   // 25 tiles per block

typedef __attribute__((ext_vector_type(8))) short short8;
typedef __attribute__((ext_vector_type(4))) short short4v;
typedef __attribute__((ext_vector_type(4))) float floatx4;

__device__ __forceinline__ short f2bf(float f) {
    union { float f; unsigned u; } v; v.f = f;
    unsigned r = (v.u + 0x7FFFu + ((v.u >> 16) & 1u)) >> 16;  // round-nearest-even
    return (short)r;
}

__device__ __forceinline__ void store_bf4(short* p, floatx4 v) {
    short4v s;
    s.x = f2bf(v.x); s.y = f2bf(v.y); s.z = f2bf(v.z); s.w = f2bf(v.w);
    *(short4v*)p = s;
}

// ---------------------------------------------------------------------------
// Prep: WcatB[n][k] (k<128: W1 = W_ne[:, :128]; k>=128: W_comb = W2 @ W_edge),
//       WselfB[n][k] = W_self — both bf16, BT[n][k] row-major.
// ---------------------------------------------------------------------------
__global__ void prep_weights(const float* __restrict__ W_edge,   // [128][32]
                             const float* __restrict__ W_ne,     // [128][256]
                             const float* __restrict__ W_self,   // [128][128]
                             short* __restrict__ WcatB,          // [128][160]
                             short* __restrict__ WselfB)         // [128][128]
{
    int idx = blockIdx.x * 256 + threadIdx.x;
    if (idx < OUT_DIM * KDIM) {
        int n = idx / KDIM, k = idx - n * KDIM;
        float val;
        if (k < IN_DIM) {
            val = W_ne[n * 256 + k];
        } else {
            int j = k - IN_DIM;
            float s = 0.f;
            for (int kk = 0; kk < 128; ++kk)
                s += W_ne[n * 256 + 128 + kk] * W_edge[kk * 32 + j];
            val = s;
        }
        WcatB[idx] = f2bf(val);
    } else if (idx < OUT_DIM * KDIM + OUT_DIM * IN_DIM) {
        int s = idx - OUT_DIM * KDIM;
        WselfB[s] = f2bf(W_self[s]);
    }
}

// ---------------------------------------------------------------------------
// Counting sort of edges by dst: histogram -> single-block scan -> scatter.
// Scatter writes ONLY the permutation (1 scattered 4B store per edge).
// ---------------------------------------------------------------------------
__global__ void hist_kernel(const int* __restrict__ dst, int* __restrict__ cnt) {
    int e = blockIdx.x * 256 + threadIdx.x;
    if (e < NEDGES) atomicAdd(&cnt[dst[e]], 1);
}

__global__ __launch_bounds__(1024) void scan_kernel(const int* __restrict__ cnt,
                                                    int* __restrict__ off2) {
    __shared__ int bufA[1024], bufB[1024];
    const int CH = 49;                       // 49*1024 = 50176 >= 50000
    int t = threadIdx.x;
    int beg = t * CH, end = min(beg + CH, NNODES);
    int s = 0;
    for (int i = beg; i < end; ++i) s += cnt[i];
    bufA[t] = s;
    __syncthreads();
    int* in = bufA; int* out = bufB;
    for (int off = 1; off < 1024; off <<= 1) {
        out[t] = in[t] + (t >= off ? in[t - off] : 0);
        __syncthreads();
        int* tmp = in; in = out; out = tmp;
    }
    int base = in[t] - s;                    // exclusive prefix of this chunk
    for (int i = beg; i < end; ++i) { off2[i] = base; base += cnt[i]; }
}

__global__ void scatter_kernel(const int* __restrict__ dst,
                               int* __restrict__ off2,       // cursor (destroyed)
                               int* __restrict__ perm) {
    int e = blockIdx.x * 256 + threadIdx.x;
    if (e < NEDGES) {
        int pos = atomicAdd(&off2[dst[e]], 1);
        perm[pos] = e;
    }
}

// ---------------------------------------------------------------------------
// Persistent edge kernel: 512 blocks; each stages B (128x160 bf16) ONCE, then
// loops over ~25 contiguous dst-sorted 64-edge tiles:
//   stage A (gather via perm) -> barrier -> MFMA -> m(bf16) to LDS -> barrier
//   -> per-column run-max over sorted dst -> one atomicMax per run.
// LDS: 21504(A) + 43008(B) + 16640(mbuf) + 512(dsts) = 81664 B -> 2 blocks/CU.
// ---------------------------------------------------------------------------
__global__ __launch_bounds__(256) void edge_kernel(
    const float* __restrict__ nfeat, const float* __restrict__ etype,
    const int* __restrict__ perm, const int* __restrict__ src,
    const int* __restrict__ dst, const float* __restrict__ b_ne,
    const short* __restrict__ WcatB, float* __restrict__ outmax)
{
    __shared__ short As[64 * A_STRIDE];
    __shared__ short Bs[128 * A_STRIDE];
    __shared__ unsigned short mbufh[64 * MS2];
    __shared__ int dsts[2][64];
    const int tid = threadIdx.x;

    // --- stage B once (L2-hot, shared by all tiles of this block) ---
    {
        int r = tid >> 1, h = tid & 1;
        const short8* g = (const short8*)(WcatB + r * KDIM + h * 80);
        short* l = Bs + r * A_STRIDE + h * 80;
        #pragma unroll
        for (int c = 0; c < 10; ++c)
            *(short8*)(l + 8 * c) = g[c];
    }

    const int lane = tid & 63;
    const int w = tid >> 6;
    const int et = w & 1;                    // edge half: rows et*32..+31
    const int nh = w >> 1;                   // out half: cols nh*64..+63
    const int li = lane & 15, q = lane >> 4;
    const short* Ab = As + (et * 32 + li) * A_STRIDE + q * 8;
    const short* Bb = Bs + (nh * 64 + li) * A_STRIDE + q * 8;

    float bias[4];
    #pragma unroll
    for (int tb = 0; tb < 4; ++tb) bias[tb] = b_ne[nh * 64 + tb * 16 + li];

    const int t0 = blockIdx.x * TPB;
    const int t1 = min(t0 + TPB, NT);

    for (int t = t0; t < t1; ++t) {
        const int e0 = t * 64;
        const int par = t & 1;

        // --- stage dsts ---
        if (tid < 64) dsts[par][tid] = dst[perm[e0 + tid]];
        // --- stage etype rows -> A cols 128..159 ---
        {
            int e = tid >> 2, c = tid & 3;   // 4 threads/edge, 8 floats each
            int pe = perm[e0 + e];
            const floatx4* row = (const floatx4*)(etype + (size_t)pe * 32);
            floatx4 v0 = row[2 * c];
            floatx4 v1 = row[2 * c + 1];
            store_bf4(As + e * A_STRIDE + IN_DIM + 8 * c, v0);
            store_bf4(As + e * A_STRIDE + IN_DIM + 8 * c + 4, v1);
        }
        // --- stage gathered nfeat rows -> A cols 0..127 ---
        {
            int g = tid & 15, eo = tid >> 4;
            #pragma unroll
            for (int p = 0; p < 4; ++p) {
                int e = eo + p * 16;
                int s = src[perm[e0 + e]];   // same line across 16 lanes
                const floatx4* row = (const floatx4*)(nfeat + (size_t)s * 128);
                floatx4 v0 = row[g];
                floatx4 v1 = row[g + 16];
                store_bf4(As + e * A_STRIDE + 4 * g, v0);
                store_bf4(As + e * A_STRIDE + 64 + 4 * g, v1);
            }
        }
        __syncthreads();                     // A ready (also: prev scan done)

        floatx4 acc[2][4];
        #pragma unroll
        for (int i = 0; i < 2; ++i)
            #pragma unroll
            for (int j = 0; j < 4; ++j)
                acc[i][j] = (floatx4){0.f, 0.f, 0.f, 0.f};

        #pragma unroll
        for (int kk = 0; kk < 5; ++kk) {
            short8 a0 = *(const short8*)(Ab + kk * 32);
            short8 a1 = *(const short8*)(Ab + 16 * A_STRIDE + kk * 32);
            short8 b0 = *(const short8*)(Bb + kk * 32);
            short8 b1 = *(const short8*)(Bb + 16 * A_STRIDE + kk * 32);
            short8 b2 = *(const short8*)(Bb + 32 * A_STRIDE + kk * 32);
            short8 b3 = *(const short8*)(Bb + 48 * A_STRIDE + kk * 32);
            acc[0][0] = __builtin_amdgcn_mfma_f32_16x16x32_bf16(a0, b0, acc[0][0], 0, 0, 0);
            acc[0][1] = __builtin_amdgcn_mfma_f32_16x16x32_bf16(a0, b1, acc[0][1], 0, 0, 0);
            acc[0][2] = __builtin_amdgcn_mfma_f32_16x16x32_bf16(a0, b2, acc[0][2], 0, 0, 0);
            acc[0][3] = __builtin_amdgcn_mfma_f32_16x16x32_bf16(a0, b3, acc[0][3], 0, 0, 0);
            acc[1][0] = __builtin_amdgcn_mfma_f32_16x16x32_bf16(a1, b0, acc[1][0], 0, 0, 0);
            acc[1][1] = __builtin_amdgcn_mfma_f32_16x16x32_bf16(a1, b1, acc[1][1], 0, 0, 0);
            acc[1][2] = __builtin_amdgcn_mfma_f32_16x16x32_bf16(a1, b2, acc[1][2], 0, 0, 0);
            acc[1][3] = __builtin_amdgcn_mfma_f32_16x16x32_bf16(a1, b3, acc[1][3], 0, 0, 0);
        }

        // --- m tile (relu+bias) -> LDS as bf16; C/D: row = q*4+reg, col = li
        #pragma unroll
        for (int ta = 0; ta < 2; ++ta) {
            #pragma unroll
            for (int r = 0; r < 4; ++r) {
                int el = et * 32 + ta * 16 + q * 4 + r;
                #pragma unroll
                for (int tb = 0; tb < 4; ++tb) {
                    int o = nh * 64 + tb * 16 + li;
                    float v = acc[ta][tb][r] + bias[tb];
                    v = v > 0.f ? v : 0.f;
                    mbufh[el * MS2 + o] = (unsigned short)f2bf(v);
                }
            }
        }
        __syncthreads();                     // mbuf ready; A reads all done

        // --- per-column run-max over dst-sorted rows; 1 atomic per run ---
        {
            int c = tid & 127, h = tid >> 7; // 2 threads/col, 32 rows each
            int r0 = h * 32;
            int curd = dsts[par][r0];
            unsigned best = mbufh[r0 * MS2 + c];
            #pragma unroll 4
            for (int r = 1; r < 32; ++r) {
                int d = dsts[par][r0 + r];
                unsigned bits = mbufh[(r0 + r) * MS2 + c];
                if (d != curd) {
                    atomicMax((int*)outmax + (size_t)curd * 128 + c,
                              (int)(best << 16));
                    curd = d; best = bits;
                } else {
                    best = best > bits ? best : bits;
                }
            }
            atomicMax((int*)outmax + (size_t)curd * 128 + c, (int)(best << 16));
        }
        // next iteration stages As/dsts[par^1] — disjoint from mbuf/dsts[par]
    }
}

// ---------------------------------------------------------------------------
// Node kernel (in-place): out = (1+eps)*out_neigh + nfeat @ W_self^T + b_self
// ---------------------------------------------------------------------------
__global__ __launch_bounds__(256) void node_kernel(
    const float* __restrict__ nfeat, const float* __restrict__ b_self,
    const float* __restrict__ eps, const short* __restrict__ WselfB,
    float* __restrict__ out)
{
    __shared__ short As[64 * NS];
    __shared__ short Bs[128 * NS];
    const int tid = threadIdx.x;
    const int n0 = blockIdx.x * 64;

    {
        int r = tid >> 1, h = tid & 1;
        const short8* g = (const short8*)(WselfB + r * 128 + h * 64);
        short* l = Bs + r * NS + h * 64;
        #pragma unroll
        for (int c = 0; c < 8; ++c)
            *(short8*)(l + 8 * c) = g[c];
    }
    {
        int r = tid >> 2, fi = tid & 3;
        int n = n0 + r;
        if (n < NNODES) {
            const floatx4* row = (const floatx4*)(nfeat + (size_t)n * 128);
            #pragma unroll
            for (int p = 0; p < 8; ++p) {
                int f = fi + 4 * p;
                store_bf4(As + r * NS + 4 * f, row[f]);
            }
        } else {
            #pragma unroll
            for (int p = 0; p < 8; ++p) {
                int f = fi + 4 * p;
                *(short4v*)(As + r * NS + 4 * f) = (short4v){0, 0, 0, 0};
            }
        }
    }
    __syncthreads();

    const int lane = tid & 63;
    const int w = tid >> 6;
    const int et = w & 1;
    const int nh = w >> 1;
    const int li = lane & 15, q = lane >> 4;

    floatx4 acc[2][4];
    #pragma unroll
    for (int i = 0; i < 2; ++i)
        #pragma unroll
        for (int j = 0; j < 4; ++j)
            acc[i][j] = (floatx4){0.f, 0.f, 0.f, 0.f};

    const short* Ab = As + (et * 32 + li) * NS + q * 8;
    const short* Bb = Bs + (nh * 64 + li) * NS + q * 8;
    #pragma unroll
    for (int kk = 0; kk < 4; ++kk) {
        short8 a0 = *(const short8*)(Ab + kk * 32);
        short8 a1 = *(const short8*)(Ab + 16 * NS + kk * 32);
        short8 b0 = *(const short8*)(Bb + kk * 32);
        short8 b1 = *(const short8*)(Bb + 16 * NS + kk * 32);
        short8 b2 = *(const short8*)(Bb + 32 * NS + kk * 32);
        short8 b3 = *(const short8*)(Bb + 48 * NS + kk * 32);
        acc[0][0] = __builtin_amdgcn_mfma_f32_16x16x32_bf16(a0, b0, acc[0][0], 0, 0, 0);
        acc[0][1] = __builtin_amdgcn_mfma_f32_16x16x32_bf16(a0, b1, acc[0][1], 0, 0, 0);
        acc[0][2] = __builtin_amdgcn_mfma_f32_16x16x32_bf16(a0, b2, acc[0][2], 0, 0, 0);
        acc[0][3] = __builtin_amdgcn_mfma_f32_16x16x32_bf16(a0, b3, acc[0][3], 0, 0, 0);
        acc[1][0] = __builtin_amdgcn_mfma_f32_16x16x32_bf16(a1, b0, acc[1][0], 0, 0, 0);
        acc[1][1] = __builtin_amdgcn_mfma_f32_16x16x32_bf16(a1, b1, acc[1][1], 0, 0, 0);
        acc[1][2] = __builtin_amdgcn_mfma_f32_16x16x32_bf16(a1, b2, acc[1][2], 0, 0, 0);
        acc[1][3] = __builtin_amdgcn_mfma_f32_16x16x32_bf16(a1, b3, acc[1][3], 0, 0, 0);
    }

    const float epsv = 1.0f + eps[0];
    #pragma unroll
    for (int ta = 0; ta < 2; ++ta) {
        #pragma unroll
        for (int r = 0; r < 4; ++r) {
            int n = n0 + et * 32 + ta * 16 + q * 4 + r;
            if (n < NNODES) {
                #pragma unroll
                for (int tb = 0; tb < 4; ++tb) {
                    int o = nh * 64 + tb * 16 + li;
                    float v = acc[ta][tb][r] + b_self[o]
                            + epsv * out[(size_t)n * 128 + o];
                    out[(size_t)n * 128 + o] = v;
                }
            }
        }
    }
}

// ---------------------------------------------------------------------------
extern "C" void kernel_launch(void* const* d_in, const int* in_sizes, int n_in,
                              void* d_out, int out_size, void* d_ws, size_t ws_size,
                              hipStream_t stream) {
    const float* nfeat  = (const float*)d_in[0];
    const float* etype  = (const float*)d_in[1];
    const int*   src    = (const int*)d_in[2];
    const int*   dst    = (const int*)d_in[3];
    const float* W_edge = (const float*)d_in[4];
    const float* W_ne   = (const float*)d_in[5];
    const float* b_ne   = (const float*)d_in[6];
    const float* W_self = (const float*)d_in[7];
    const float* b_self = (const float*)d_in[8];
    const float* eps    = (const float*)d_in[9];
    float* out = (float*)d_out;

    char* ws = (char*)d_ws;
    size_t off = 0;
    auto alloc = [&](size_t bytes) { void* p = ws + off; off = (off + bytes + 255) & ~(size_t)255; return p; };
    int*   cnt    = (int*)alloc((size_t)NNODES * 4);
    int*   off2   = (int*)alloc((size_t)NNODES * 4);
    int*   perm   = (int*)alloc((size_t)NEDGES * 4);
    short* WcatB  = (short*)alloc((size_t)OUT_DIM * KDIM * 2);
    short* WselfB = (short*)alloc((size_t)OUT_DIM * IN_DIM * 2);

    hipMemsetAsync(cnt, 0, (size_t)NNODES * 4, stream);
    hipMemsetAsync(out, 0, (size_t)NNODES * 128 * sizeof(float), stream);
    prep_weights<<<144, 256, 0, stream>>>(W_edge, W_ne, W_self, WcatB, WselfB);
    hist_kernel<<<(NEDGES + 255) / 256, 256, 0, stream>>>(dst, cnt);
    scan_kernel<<<1, 1024, 0, stream>>>(cnt, off2);
    scatter_kernel<<<(NEDGES + 255) / 256, 256, 0, stream>>>(dst, off2, perm);
    edge_kernel<<<EG, 256, 0, stream>>>(nfeat, etype, perm, src, dst, b_ne,
                                        WcatB, out);
    node_kernel<<<(NNODES + 63) / 64, 256, 0, stream>>>(nfeat, b_self, eps,
                                                        WselfB, out);
}